// Round 6
// baseline (1415.021 us; speedup 1.0000x reference)
//
#include <hip/hip_runtime.h>
#include <hip/hip_bf16.h>
#include <math.h>

// PointNet++ SAModule: FPS -> ball query -> PointNetConv(MLP, max-agg)
// B=16, N=4096, S=1024, K=64, r=0.1, MLP 67->64->64->128.
// Selection decisions (FPS argmax, ball membership, top-K) bit-exact vs numpy.
// R6: (a) FPS reduce = pure-DPP ladder (shr1/2/4/8 + bcast15/31) carrying xyz,
//     no LDS round trips before the single barrier.
//     (b) conv = W columns in registers (full unroll), x_j staged in LDS,
//     h rows read as float4 broadcast ds_read_b128.

#define NB 16
#define NP 4096
#define FIN 64
#define NS 1024
#define KN 64
#define CAP 256

__device__ __forceinline__ float dist2e(float ax, float ay, float az,
                                        float bx, float by, float bz) {
    float dx = __fsub_rn(ax, bx);
    float dy = __fsub_rn(ay, by);
    float dz = __fsub_rn(az, bz);
    return __fadd_rn(__fadd_rn(__fmul_rn(dx, dx), __fmul_rn(dy, dy)),
                     __fmul_rn(dz, dz));
}

// One DPP reduce level on packed u64 key (max) carrying xyz payload.
// CTRL literal: 0x111=shr1 0x112=shr2 0x114=shr4 0x118=shr8 0x142=bcast15
// 0x143=bcast31. bound_ctrl=false + old=self => masked lanes keep own value.
#define DPP_LVL(CTRL)                                                          \
    do {                                                                       \
        int _lo = (int)(unsigned)(key & 0xFFFFFFFFull);                        \
        int _hi = (int)(unsigned)(key >> 32);                                  \
        int _nlo = __builtin_amdgcn_update_dpp(_lo, _lo, CTRL, 0xF, 0xF, false);\
        int _nhi = __builtin_amdgcn_update_dpp(_hi, _hi, CTRL, 0xF, 0xF, false);\
        int _nx = __builtin_amdgcn_update_dpp(xi, xi, CTRL, 0xF, 0xF, false);  \
        int _ny = __builtin_amdgcn_update_dpp(yi, yi, CTRL, 0xF, 0xF, false);  \
        int _nz = __builtin_amdgcn_update_dpp(zi, zi, CTRL, 0xF, 0xF, false);  \
        unsigned long long _nk =                                               \
            ((unsigned long long)(unsigned)_nhi << 32) | (unsigned)_nlo;       \
        if (_nk > key) { key = _nk; xi = _nx; yi = _ny; zi = _nz; }            \
    } while (0)

// ---------------- FPS: one block per cloud, 256 thr, 16 pts/thread ----------
__global__ __launch_bounds__(256) void fps_kernel(const float* __restrict__ pos,
                                                  int* __restrict__ fps_idx,
                                                  float* __restrict__ out_pos,
                                                  float* __restrict__ out_batch) {
    const int b = blockIdx.x;
    const int tid = threadIdx.x;
    const int lane = tid & 63;
    const int wv = tid >> 6;
    __shared__ float px[NP], py[NP], pz[NP];
    __shared__ __align__(16) float bc[2][4][8];  // {key_lo,key_hi,x,y,z,pad3}
    const float* p = pos + (size_t)b * NP * 3;
    float lx[16], ly[16], lz[16], md[16];
#pragma unroll
    for (int i = 0; i < 16; ++i) {
        int j = tid + (i << 8);
        float x = p[j * 3 + 0];
        float y = p[j * 3 + 1];
        float z = p[j * 3 + 2];
        px[j] = x; py[j] = y; pz[j] = z;
        lx[i] = x; ly[i] = y; lz[i] = z;
        md[i] = INFINITY;
    }
    __syncthreads();
    if (tid == 0) {
        fps_idx[b * NS] = 0;
        out_pos[(size_t)(b * NS) * 3 + 0] = px[0];
        out_pos[(size_t)(b * NS) * 3 + 1] = py[0];
        out_pos[(size_t)(b * NS) * 3 + 2] = pz[0];
    }
    float cx = px[0], cy = py[0], cz = pz[0];
    for (int s = 1; s < NS; ++s) {
        // local md update + per-lane argmax (ascending i + strict > keeps
        // the lowest index, matching np.argmax first-occurrence)
        float bv = -1.0f;
        int bi = 0;
        float bpx = 0.f, bpy = 0.f, bpz = 0.f;
#pragma unroll
        for (int i = 0; i < 16; ++i) {
            float d = dist2e(lx[i], ly[i], lz[i], cx, cy, cz);
            float m = md[i];
            m = d < m ? d : m;   // jnp.minimum (exact)
            md[i] = m;
            bool take = (m > bv);
            bv = take ? m : bv;
            bi = take ? (tid + (i << 8)) : bi;
            bpx = take ? lx[i] : bpx;
            bpy = take ? ly[i] : bpy;
            bpz = take ? lz[i] : bpz;
        }
        // pack: positive-f32 bits order-isomorphic; ~idx => tie -> lower idx
        unsigned long long key =
            ((unsigned long long)__float_as_uint(bv) << 32) |
            (unsigned)(~(unsigned)bi);
        int xi = __float_as_int(bpx);
        int yi = __float_as_int(bpy);
        int zi = __float_as_int(bpz);
        // pure-DPP wave reduce; winner (key+xyz) lands in lane 63
        DPP_LVL(0x111);
        DPP_LVL(0x112);
        DPP_LVL(0x114);
        DPP_LVL(0x118);
        DPP_LVL(0x142);
        DPP_LVL(0x143);
        const int buf = s & 1;  // double buffer -> one barrier per step
        if (lane == 63) {
            bc[buf][wv][0] = __uint_as_float((unsigned)(key & 0xFFFFFFFFull));
            bc[buf][wv][1] = __uint_as_float((unsigned)(key >> 32));
            bc[buf][wv][2] = __int_as_float(xi);
            bc[buf][wv][3] = __int_as_float(yi);
            bc[buf][wv][4] = __int_as_float(zi);
        }
        __syncthreads();
        // all lanes: select best of the 4 wave candidates (key + xyz folded)
        unsigned long long bk;
        float bx, by, bz;
        {
            float4 e = *(const float4*)&bc[buf][0][0];
            bk = ((unsigned long long)__float_as_uint(e.y) << 32) |
                 __float_as_uint(e.x);
            bx = e.z; by = e.w; bz = bc[buf][0][4];
        }
#pragma unroll
        for (int w = 1; w < 4; ++w) {
            float4 e = *(const float4*)&bc[buf][w][0];
            unsigned long long k2 =
                ((unsigned long long)__float_as_uint(e.y) << 32) |
                __float_as_uint(e.x);
            float z2 = bc[buf][w][4];
            bool take = (k2 > bk);
            bk = take ? k2 : bk;
            bx = take ? e.z : bx;
            by = take ? e.w : by;
            bz = take ? z2 : bz;
        }
        const int cur = (int)(~(unsigned)(bk & 0xFFFFFFFFull));
        cx = bx; cy = by; cz = bz;
        if (tid == 0) {
            fps_idx[b * NS + s] = cur;
            out_pos[(size_t)(b * NS + s) * 3 + 0] = bx;
            out_pos[(size_t)(b * NS + s) * 3 + 1] = by;
            out_pos[(size_t)(b * NS + s) * 3 + 2] = bz;
        }
    }
    for (int s = tid; s < NS; s += 256) out_batch[b * NS + s] = (float)b;
}

// ------------- ball query: 16 blocks/cloud, 64 centers/block, wave/center ----
__global__ __launch_bounds__(256) void ball_kernel(const float* __restrict__ pos,
                                                   const int* __restrict__ fps_idx,
                                                   int* __restrict__ nbr_cnt,
                                                   int* __restrict__ nbr_idx) {
    __shared__ float px[NP], py[NP], pz[NP];
    __shared__ float cd2[4][CAP];
    __shared__ int cix[4][CAP];
    const int tid = threadIdx.x;
    const int wv = tid >> 6, lane = tid & 63;
    const int b = blockIdx.x >> 4;
    const int grp = blockIdx.x & 15;
    const float* p = pos + (size_t)b * NP * 3;
    for (int e = tid; e < NP; e += 256) {
        px[e] = p[e * 3 + 0];
        py[e] = p[e * 3 + 1];
        pz[e] = p[e * 3 + 2];
    }
    __syncthreads();
    for (int i = 0; i < 16; ++i) {
        const int s = grp * 64 + i * 4 + wv;
        const int cen = b * NS + s;
        const int ci = fps_idx[cen];
        const float cx = px[ci], cy = py[ci], cz = pz[ci];
        int cnt = 0;
        for (int it = 0; it < NP / 64; ++it) {
            const int j = it * 64 + lane;
            float d2 = dist2e(cx, cy, cz, px[j], py[j], pz[j]);
            bool in = (d2 <= 0.01f);  // f32(0.1*0.1)
            unsigned long long m = __ballot(in);
            if (in) {
                int slot = cnt + __popcll(m & ((1ull << lane) - 1ull));
                if (slot < CAP) { cd2[wv][slot] = d2; cix[wv][slot] = j; }
            }
            cnt += __popcll(m);
        }
        if (cnt > CAP) cnt = CAP;
        const int keep = cnt <= KN ? cnt : KN;
        if (lane == 0) nbr_cnt[cen] = keep;
        if (cnt <= KN) {
            if (lane < cnt) nbr_idx[(size_t)cen * KN + lane] = cix[wv][lane];
        } else {
            // exact K-nearest: rank by (d2, idx) lexicographic (top_k order)
            for (int e = lane; e < cnt; e += 64) {
                float d = cd2[wv][e];
                int id = cix[wv][e];
                int rank = 0;
                for (int q = 0; q < cnt; ++q) {
                    float dq = cd2[wv][q];
                    int iq = cix[wv][q];
                    rank += (dq < d || (dq == d && iq < id)) ? 1 : 0;
                }
                if (rank < KN) nbr_idx[(size_t)cen * KN + rank] = id;
            }
        }
    }
}

// ------- PointNetConv: block per center; W in regs, x_j/h in LDS (float4) ----
__global__ __launch_bounds__(256) void conv_kernel(const float* __restrict__ pos,
                                                   const float* __restrict__ x,
                                                   const int* __restrict__ fps_idx,
                                                   const int* __restrict__ nbr_cnt,
                                                   const int* __restrict__ nbr_idx,
                                                   const float* __restrict__ W1,
                                                   const float* __restrict__ b1,
                                                   const float* __restrict__ W2,
                                                   const float* __restrict__ b2,
                                                   const float* __restrict__ W3,
                                                   const float* __restrict__ b3,
                                                   float* __restrict__ out) {
    const int cen = blockIdx.x;
    const int b = cen >> 10;  // NS = 1024
    const int tid = threadIdx.x;
    const int lane = tid & 63;
    const int wv = tid >> 6;
    __shared__ __align__(16) float xj[KN][FIN];  // gathered x_j rows
    __shared__ __align__(16) float h1[KN][FIN];
    __shared__ __align__(16) float h2[KN][FIN];
    __shared__ float dpx[KN], dpy[KN], dpz[KN];
    __shared__ int jr[KN];
    __shared__ float omax[128];
    const int C = nbr_cnt[cen];
    const int ci = fps_idx[cen];
    const float* pb = pos + (size_t)b * NP * 3;
    if (tid < KN && tid < C) {
        int j = nbr_idx[(size_t)cen * KN + tid];
        jr[tid] = b * NP + j;
        float cx = pb[ci * 3 + 0], cy = pb[ci * 3 + 1], cz = pb[ci * 3 + 2];
        dpx[tid] = __fsub_rn(pb[j * 3 + 0], cx);
        dpy[tid] = __fsub_rn(pb[j * 3 + 1], cy);
        dpz[tid] = __fsub_rn(pb[j * 3 + 2], cz);
    }
    __syncthreads();
    // stage x_j rows: wave wv handles rows wv, wv+4, ... (coalesced 256B/wave)
    for (int row = wv; row < C; row += 4) {
        xj[row][lane] = x[(size_t)jr[row] * FIN + lane];
    }
    __syncthreads();
    const int c = lane;
    const int pg = wv;
    {  // layer 1: W1 column c in regs (full unroll -> static reg indexing)
        float w1r[FIN];
#pragma unroll
        for (int f = 0; f < FIN; ++f) w1r[f] = W1[f * 64 + c];
        const float w1x = W1[64 * 64 + c];
        const float w1y = W1[65 * 64 + c];
        const float w1z = W1[66 * 64 + c];
        const float bb = b1[c];
        for (int p = pg; p < C; p += 4) {
            float acc = bb + dpx[p] * w1x + dpy[p] * w1y + dpz[p] * w1z;
#pragma unroll
            for (int f4 = 0; f4 < FIN / 4; ++f4) {
                float4 v = *(const float4*)&xj[p][f4 * 4];  // broadcast b128
                acc = fmaf(v.x, w1r[f4 * 4 + 0], acc);
                acc = fmaf(v.y, w1r[f4 * 4 + 1], acc);
                acc = fmaf(v.z, w1r[f4 * 4 + 2], acc);
                acc = fmaf(v.w, w1r[f4 * 4 + 3], acc);
            }
            h1[p][c] = acc > 0.f ? acc : 0.f;
        }
    }
    __syncthreads();
    {  // layer 2
        float w2r[FIN];
#pragma unroll
        for (int k = 0; k < FIN; ++k) w2r[k] = W2[k * 64 + c];
        const float bb = b2[c];
        for (int p = pg; p < C; p += 4) {
            float acc = bb;
#pragma unroll
            for (int f4 = 0; f4 < FIN / 4; ++f4) {
                float4 v = *(const float4*)&h1[p][f4 * 4];
                acc = fmaf(v.x, w2r[f4 * 4 + 0], acc);
                acc = fmaf(v.y, w2r[f4 * 4 + 1], acc);
                acc = fmaf(v.z, w2r[f4 * 4 + 2], acc);
                acc = fmaf(v.w, w2r[f4 * 4 + 3], acc);
            }
            h2[p][c] = acc > 0.f ? acc : 0.f;
        }
    }
    __syncthreads();
    const int o = tid & 127;
    const int g2 = tid >> 7;
    {  // layer 3 + max aggregation, W3 column o in regs
        float w3r[FIN];
#pragma unroll
        for (int k = 0; k < FIN; ++k) w3r[k] = W3[k * 128 + o];
        const float bb = b3[o];
        float mx = -INFINITY;
        for (int p = g2; p < C; p += 2) {
            float acc = bb;
#pragma unroll
            for (int f4 = 0; f4 < FIN / 4; ++f4) {
                float4 v = *(const float4*)&h2[p][f4 * 4];
                acc = fmaf(v.x, w3r[f4 * 4 + 0], acc);
                acc = fmaf(v.y, w3r[f4 * 4 + 1], acc);
                acc = fmaf(v.z, w3r[f4 * 4 + 2], acc);
                acc = fmaf(v.w, w3r[f4 * 4 + 3], acc);
            }
            acc = acc > 0.f ? acc : 0.f;
            mx = mx > acc ? mx : acc;
        }
        if (g2 == 0) omax[o] = mx;
        __syncthreads();
        if (g2 == 1) {
            float other = omax[o];
            mx = mx > other ? mx : other;
            out[(size_t)cen * 128 + o] = mx;
        }
    }
}

extern "C" void kernel_launch(void* const* d_in, const int* in_sizes, int n_in,
                              void* d_out, int out_size, void* d_ws, size_t ws_size,
                              hipStream_t stream) {
    const float* x   = (const float*)d_in[0];
    const float* pos = (const float*)d_in[1];
    const float* W1  = (const float*)d_in[3];
    const float* b1  = (const float*)d_in[4];
    const float* W2  = (const float*)d_in[5];
    const float* b2  = (const float*)d_in[6];
    const float* W3  = (const float*)d_in[7];
    const float* b3  = (const float*)d_in[8];
    float* out = (float*)d_out;
    char* ws = (char*)d_ws;
    int* fps_idx = (int*)(ws);                     // 16384 * 4 B
    int* nbr_cnt = (int*)(ws + 16384 * 4);         // 16384 * 4 B
    int* nbr_idx = (int*)(ws + 16384 * 8);         // 16384 * 64 * 4 B = 4 MB
    float* out_feat  = out;                         // [16384][128]
    float* out_pos   = out + (size_t)16384 * 128;   // [16384][3]
    float* out_batch = out + (size_t)16384 * 131;   // [16384]
    fps_kernel<<<NB, 256, 0, stream>>>(pos, fps_idx, out_pos, out_batch);
    ball_kernel<<<NB * 16, 256, 0, stream>>>(pos, fps_idx, nbr_cnt, nbr_idx);
    conv_kernel<<<NB * NS, 256, 0, stream>>>(pos, x, fps_idx, nbr_cnt, nbr_idx,
                                             W1, b1, W2, b2, W3, b3, out_feat);
}